// Round 19
// baseline (196.936 us; speedup 1.0000x reference)
//
#include <hip/hip_runtime.h>
#include <hip/hip_bf16.h>

#define NPIX 4096
#define FEAT 128
#define LAT 64
#define BS 64
#define NSTEPS 6

// flat f32 output offsets (log_m_k, log_s_k, c_f, delta, seeds)
#define OFF_LOGM  0u
#define OFF_LOGS  1835008u
#define OFF_CF    3670016u
#define OFF_DELTA 20447232u
#define OFF_SEEDS 20971520u

typedef float f32x4 __attribute__((ext_vector_type(4)));
typedef short s16x8 __attribute__((ext_vector_type(8)));

__device__ __forceinline__ void amax_comb(float& bv, int& bi, float v, int i) {
    if (v > bv || (v == bv && i < bi)) { bv = v; bi = i; }
}

__device__ __forceinline__ short f2bf_rne(float r) {
    __hip_bfloat16 h = __float2bfloat16(r);
    return __builtin_bit_cast(short, h);
}

// split f32 into bf16 hi (truncated -> exact residual) + bf16 lo (RNE of residual)
__device__ __forceinline__ void split2(float v, short& hi, short& lo) {
    unsigned u = __builtin_bit_cast(unsigned, v);
    hi = (short)(u >> 16);
    float hf = __builtin_bit_cast(float, u & 0xFFFF0000u);
    lo = f2bf_rne(v - hf);
}

// 4x4 transpose among the 4 lanes of a quad (b = lane&3).
__device__ __forceinline__ void transpose4(float4& v, int b) {
    float4 w;
    w.x = __shfl_xor(v.x, 1, 64); w.y = __shfl_xor(v.y, 1, 64);
    w.z = __shfl_xor(v.z, 1, 64); w.w = __shfl_xor(v.w, 1, 64);
    float4 u;
    if ((b & 1) == 0) u = make_float4(v.x, w.x, v.z, w.z);
    else              u = make_float4(w.y, v.y, w.w, v.w);
    float4 w2;
    w2.x = __shfl_xor(u.x, 2, 64); w2.y = __shfl_xor(u.y, 2, 64);
    w2.z = __shfl_xor(u.z, 2, 64); w2.w = __shfl_xor(u.w, 2, 64);
    if ((b & 2) == 0) v = make_float4(u.x, u.y, w2.x, w2.y);
    else              v = make_float4(w2.z, w2.w, u.z, u.w);
}

// AGPR park/unpark primitives (32-bit)
#define AWR(d, s) asm volatile("v_accvgpr_write_b32 %0, %1" : "=a"(d) : "v"(s));
#define ARD(d, s) asm volatile("v_accvgpr_read_b32 %0, %1" : "=v"(d) : "a"(s));

// ---------------------------------------------------------------------------
// K0: split gate*W into bf16 hi/lo in global scratch (16KB each, L2-resident).
// ---------------------------------------------------------------------------
__global__ void prep_w(const float* __restrict__ w, const float* __restrict__ gate_p,
                       short* __restrict__ gwh, short* __restrict__ gwl)
{
    int i = blockIdx.x * 256 + threadIdx.x;   // 8192 total
    float v = gate_p[0] * w[i];
    short h, l; split2(v, h, l);
    gwh[i] = h; gwl[i] = l;
}

// ---------------------------------------------------------------------------
// K1: 1x1 conv via split-bf16 MFMA — r9 structure, W moved LDS -> AGPRs:
// each thread's 16 W-fragments (its own oh/l15/lg rows, all 4 K-chunks) are
// parked in 64 AGPRs via "a" constraints (allocator must honor; r16-proven)
// and unparked 4/chunk (16 v_accvgpr_read = trivial). LDS drops 75->41 KB
// -> 3 blocks/CU (24 waves) to hide the per-chunk vmcnt drain that capped
// every 2-block variant at ~78us. X staging identical to r9.
// 512 thr = 8 waves; wave w: px quarter (w&3)*64, output half (w>>2)*32.
// grid = 64 b x 16 tiles(256 px) = 1024 blocks.
// ---------------------------------------------------------------------------

#define WFRAG_DECL(kc) \
    float wh_##kc##_0_0, wh_##kc##_0_1, wh_##kc##_0_2, wh_##kc##_0_3; \
    float wh_##kc##_1_0, wh_##kc##_1_1, wh_##kc##_1_2, wh_##kc##_1_3; \
    float wl_##kc##_0_0, wl_##kc##_0_1, wl_##kc##_0_2, wl_##kc##_0_3; \
    float wl_##kc##_1_0, wl_##kc##_1_1, wl_##kc##_1_2, wl_##kc##_1_3;

#define WFRAG_PARK(kc) { \
    uint4 h0 = *(const uint4*)&gwh[(oh * 32 + 0 * 16 + l15) * 128 + kc * 32 + lg * 8]; \
    uint4 h1 = *(const uint4*)&gwh[(oh * 32 + 1 * 16 + l15) * 128 + kc * 32 + lg * 8]; \
    uint4 l0 = *(const uint4*)&gwl[(oh * 32 + 0 * 16 + l15) * 128 + kc * 32 + lg * 8]; \
    uint4 l1 = *(const uint4*)&gwl[(oh * 32 + 1 * 16 + l15) * 128 + kc * 32 + lg * 8]; \
    AWR(wh_##kc##_0_0, h0.x) AWR(wh_##kc##_0_1, h0.y) AWR(wh_##kc##_0_2, h0.z) AWR(wh_##kc##_0_3, h0.w) \
    AWR(wh_##kc##_1_0, h1.x) AWR(wh_##kc##_1_1, h1.y) AWR(wh_##kc##_1_2, h1.z) AWR(wh_##kc##_1_3, h1.w) \
    AWR(wl_##kc##_0_0, l0.x) AWR(wl_##kc##_0_1, l0.y) AWR(wl_##kc##_0_2, l0.z) AWR(wl_##kc##_0_3, l0.w) \
    AWR(wl_##kc##_1_0, l1.x) AWR(wl_##kc##_1_1, l1.y) AWR(wl_##kc##_1_2, l1.z) AWR(wl_##kc##_1_3, l1.w) }

#define WFRAG_UNPARK(kc, Ah, Al) { \
    unsigned u0, u1, u2, u3; uint4 uu; \
    ARD(u0, wh_##kc##_0_0) ARD(u1, wh_##kc##_0_1) ARD(u2, wh_##kc##_0_2) ARD(u3, wh_##kc##_0_3) \
    uu = make_uint4(u0, u1, u2, u3); Ah[0] = __builtin_bit_cast(s16x8, uu); \
    ARD(u0, wh_##kc##_1_0) ARD(u1, wh_##kc##_1_1) ARD(u2, wh_##kc##_1_2) ARD(u3, wh_##kc##_1_3) \
    uu = make_uint4(u0, u1, u2, u3); Ah[1] = __builtin_bit_cast(s16x8, uu); \
    ARD(u0, wl_##kc##_0_0) ARD(u1, wl_##kc##_0_1) ARD(u2, wl_##kc##_0_2) ARD(u3, wl_##kc##_0_3) \
    uu = make_uint4(u0, u1, u2, u3); Al[0] = __builtin_bit_cast(s16x8, uu); \
    ARD(u0, wl_##kc##_1_0) ARD(u1, wl_##kc##_1_1) ARD(u2, wl_##kc##_1_2) ARD(u3, wl_##kc##_1_3) \
    uu = make_uint4(u0, u1, u2, u3); Al[1] = __builtin_bit_cast(s16x8, uu); }

#define STAGE_WRITE() { \
    _Pragma("unroll") \
    for (int i = 0; i < 4; ++i) { \
        int g = g0 + 2 * i; \
        float4 t = v[i]; transpose4(t, j); \
        short h0, l0, h1, l1, h2, l2, h3, l3; \
        split2(t.x, h0, l0); split2(t.y, h1, l1); \
        split2(t.z, h2, l2); split2(t.w, h3, l3); \
        *(short4*)&Xhi[P + j][g * 4] = make_short4(h0, h1, h2, h3); \
        *(short4*)&Xlo[P + j][g * 4] = make_short4(l0, l1, l2, l3); \
    } }

#define CHUNK(kc) { \
    if (kc < 3) { \
        _Pragma("unroll") \
        for (int i = 0; i < 4; ++i) { \
            int g = g0 + 2 * i; \
            v[i] = *(const float4*)(xb + (size_t)((kc + 1) * 32 + g * 4 + j) * NPIX + P); \
        } \
    } \
    s16x8 Ah[2], Al[2]; \
    WFRAG_UNPARK(kc, Ah, Al) \
    _Pragma("unroll") \
    for (int pg = 0; pg < 4; ++pg) { \
        int pxl = pxq * 64 + pg * 16 + l15; \
        s16x8 Bh = *(const s16x8*)&Xhi[pxl][lg * 8]; \
        s16x8 Bl = *(const s16x8*)&Xlo[pxl][lg * 8]; \
        _Pragma("unroll") \
        for (int og2 = 0; og2 < 2; ++og2) { \
            acc[og2][pg] = __builtin_amdgcn_mfma_f32_16x16x32_bf16(Ah[og2], Bh, acc[og2][pg], 0, 0, 0); \
            acc[og2][pg] = __builtin_amdgcn_mfma_f32_16x16x32_bf16(Ah[og2], Bl, acc[og2][pg], 0, 0, 0); \
            acc[og2][pg] = __builtin_amdgcn_mfma_f32_16x16x32_bf16(Al[og2], Bh, acc[og2][pg], 0, 0, 0); \
        } \
    } \
    if (kc < 3) { \
        __syncthreads(); \
        STAGE_WRITE() \
        __syncthreads(); \
    } }

__global__ __launch_bounds__(512, 6) void conv_mfma(
    const float* __restrict__ x, const float* __restrict__ rand_pixel,
    const float* __restrict__ bias, const float* __restrict__ gate_p,
    float* __restrict__ out,
    float* __restrict__ pval, int* __restrict__ pidx, int* __restrict__ cnt,
    const short* __restrict__ gwh, const short* __restrict__ gwl)
{
    __shared__ __align__(16) short Xhi[256][40];   // pitch 80B
    __shared__ __align__(16) short Xlo[256][40];
    __shared__ float sbias[64];

    const int tid  = threadIdx.x;
    const int b    = blockIdx.x >> 4;
    const int tile = blockIdx.x & 15;
    const int p0   = tile * 256;
    const int lane = tid & 63;
    const int wv   = tid >> 6;
    const int l15  = lane & 15;
    const int lg   = lane >> 4;
    const int oh   = wv >> 2;
    const int pxq  = wv & 3;

    const int q  = tid >> 2;
    const int j  = tid & 3;
    const int P  = (q & 63) * 4;
    const int g0 = q >> 6;

    if (tile == 0 && tid < 8) cnt[b * 8 + tid] = 0;
    if (tid < 64) sbias[tid] = gate_p[0] * bias[tid];

    // park all 16 W fragments in AGPRs (L2-hot source, once per block)
    WFRAG_DECL(0) WFRAG_DECL(1) WFRAG_DECL(2) WFRAG_DECL(3)
    WFRAG_PARK(0) WFRAG_PARK(1) WFRAG_PARK(2) WFRAG_PARK(3)

    // stage X chunk 0
    const float* xb = x + (size_t)b * FEAT * NPIX + p0;
    float4 v[4];
    #pragma unroll
    for (int i = 0; i < 4; ++i) {
        int g = g0 + 2 * i;
        v[i] = *(const float4*)(xb + (size_t)(g * 4 + j) * NPIX + P);
    }
    STAGE_WRITE()
    __syncthreads();

    f32x4 acc[2][4];
    #pragma unroll
    for (int og2 = 0; og2 < 2; ++og2)
        #pragma unroll
        for (int pg = 0; pg < 4; ++pg)
            acc[og2][pg] = (f32x4){0.f, 0.f, 0.f, 0.f};

    CHUNK(0) CHUNK(1) CHUNK(2) CHUNK(3)

    // epilogue: D mapping col=l15 (pixel), row=4*lg+r
    float* cf = out + OFF_CF + (size_t)b * LAT * NPIX;
    #pragma unroll
    for (int og2 = 0; og2 < 2; ++og2) {
        #pragma unroll
        for (int pg = 0; pg < 4; ++pg) {
            #pragma unroll
            for (int r = 0; r < 4; ++r) {
                int o = oh * 32 + og2 * 16 + lg * 4 + r;
                int p = p0 + pxq * 64 + pg * 16 + l15;
                float vv = acc[og2][pg][r] + sbias[o];
                if (o == 62) {
                    out[OFF_DELTA + ((size_t)b * 2 + 0) * NPIX + p] = vv;
                    vv += (float)(-1.0 + 2.0 * (double)(p >> 6) / 63.0);
                } else if (o == 63) {
                    out[OFF_DELTA + ((size_t)b * 2 + 1) * NPIX + p] = vv;
                    vv += (float)(-1.0 + 2.0 * (double)(p & 63) / 63.0);
                }
                cf[(size_t)o * NPIX + p] = vv;
            }
        }
    }

    if (wv == 0) {
        *(float4*)(out + OFF_LOGS + (size_t)b * NPIX + p0 + lane * 4) =
            make_float4(0.f, 0.f, 0.f, 0.f);
        float4 rv = *(const float4*)(rand_pixel + (size_t)b * NPIX + p0 + lane * 4);
        int pb = p0 + lane * 4;
        float bv = rv.x; int bi = pb;
        if (rv.y > bv) { bv = rv.y; bi = pb + 1; }
        if (rv.z > bv) { bv = rv.z; bi = pb + 2; }
        if (rv.w > bv) { bv = rv.w; bi = pb + 3; }
        #pragma unroll
        for (int off = 32; off > 0; off >>= 1) {
            float ov = __shfl_down(bv, off, 64);
            int   oi = __shfl_down(bi, off, 64);
            amax_comb(bv, bi, ov, oi);
        }
        if (lane == 0) { pval[blockIdx.x] = bv; pidx[blockIdx.x] = bi; }
    }
}

// 16 groups of 4 channels
#define REP16(OP) OP(0) OP(1) OP(2) OP(3) OP(4) OP(5) OP(6) OP(7) \
                  OP(8) OP(9) OP(10) OP(11) OP(12) OP(13) OP(14) OP(15)

// ---------------------------------------------------------------------------
// K2: fused 6-step clustering — r16/r18 champion, verbatim. cr[64] parked in
// AGPRs; XCD-local batch decode; block 1024 thr, grid 256, quorum-4 spins.
// ---------------------------------------------------------------------------
__global__ __launch_bounds__(1024, 4) void steps_fused(
    const float* __restrict__ rand_pixel, const float* __restrict__ log_sigma_p,
    float* __restrict__ out, float* pv, int* pi, int* cnt)
{
    __shared__ float s_mv[16];
    __shared__ int   s_mi[16];
    __shared__ __align__(16) float s_seed[LAT];
    __shared__ float s_rv[16];
    __shared__ int   s_ri[16];

    const int tid  = threadIdx.x;
    const int b    = blockIdx.x & 63;    // XCD-local decode
    const int tile = blockIdx.x >> 6;    // 0..3
    const int p    = tile * 1024 + tid;

    const float* cfb = out + OFF_CF + (size_t)b * LAT * NPIX;

#define AG_DECL(i) float ag##i##_0, ag##i##_1, ag##i##_2, ag##i##_3;
    REP16(AG_DECL)
#define AG_PARK(i) { \
    float v0 = cfb[(size_t)(4*i+0)*NPIX + p]; \
    float v1 = cfb[(size_t)(4*i+1)*NPIX + p]; \
    float v2 = cfb[(size_t)(4*i+2)*NPIX + p]; \
    float v3 = cfb[(size_t)(4*i+3)*NPIX + p]; \
    AWR(ag##i##_0, v0) AWR(ag##i##_1, v1) AWR(ag##i##_2, v2) AWR(ag##i##_3, v3) }
    REP16(AG_PARK)

    const float rp    = rand_pixel[(size_t)b * NPIX + p];
    const float sigma = expf(log_sigma_p[0]);
    float ls = 0.f;

    #pragma unroll 1
    for (int s = 0; s < NSTEPS; ++s) {
        if (s > 0) {
            if (tid == 0) {
                while (__hip_atomic_load(&cnt[b * 8 + s], __ATOMIC_ACQUIRE,
                                         __HIP_MEMORY_SCOPE_AGENT) < 4)
                    __builtin_amdgcn_s_sleep(2);
            }
            __syncthreads();
        }
        const int nmerge = (s == 0) ? 16 : 4;
        if (tid < nmerge) {
            s_mv[tid] = __hip_atomic_load(&pv[(s * BS + b) * 16 + tid],
                                          __ATOMIC_RELAXED, __HIP_MEMORY_SCOPE_AGENT);
            s_mi[tid] = __hip_atomic_load(&pi[(s * BS + b) * 16 + tid],
                                          __ATOMIC_RELAXED, __HIP_MEMORY_SCOPE_AGENT);
        }
        __syncthreads();

        float bv = -1.0f; int bi = 0;
        for (int k = 0; k < nmerge; ++k) amax_comb(bv, bi, s_mv[k], s_mi[k]);

        if (tid < LAT) s_seed[tid] = cfb[(size_t)tid * NPIX + bi];
        __syncthreads();
        if (tile == 0 && tid < LAT)
            out[OFF_SEEDS + ((size_t)s * BS + b) * LAT + tid] = s_seed[tid];

        float d2 = 0.f;
#define AG_DIFF(i) { \
        float c0, c1, c2, c3; \
        ARD(c0, ag##i##_0) ARD(c1, ag##i##_1) ARD(c2, ag##i##_2) ARD(c3, ag##i##_3) \
        float e0 = c0 - s_seed[4*i+0]; d2 = fmaf(e0, e0, d2); \
        float e1 = c1 - s_seed[4*i+1]; d2 = fmaf(e1, e1, d2); \
        float e2 = c2 - s_seed[4*i+2]; d2 = fmaf(e2, e2, d2); \
        float e3 = c3 - s_seed[4*i+3]; d2 = fmaf(e3, e3, d2); }
        REP16(AG_DIFF)

        float dist  = sqrtf(fminf(fmaxf(d2, 1e-10f), 1e10f));
        float alpha = expf(-dist / sigma);
        alpha = fminf(fmaxf(alpha, 0.01f), 0.99f);
        float lm  = ls + logf(alpha);
        float lsn = ls + log1pf(-alpha);

        out[OFF_LOGM + ((size_t)s * BS + b) * NPIX + p]       = lm;
        out[OFF_LOGS + ((size_t)(s + 1) * BS + b) * NPIX + p] = lsn;
        ls = lsn;

        if (s == NSTEPS - 1) {
            out[OFF_LOGM + ((size_t)NSTEPS * BS + b) * NPIX + p] = lsn;
        } else {
            float prob = rp * expf(lsn);
            int   idx  = p;
            #pragma unroll
            for (int off = 32; off > 0; off >>= 1) {
                float ov = __shfl_down(prob, off, 64);
                int   oi = __shfl_down(idx, off, 64);
                amax_comb(prob, idx, ov, oi);
            }
            int lane = tid & 63, wid = tid >> 6;
            if (lane == 0) { s_rv[wid] = prob; s_ri[wid] = idx; }
            __syncthreads();
            if (tid == 0) {
                float fb = s_rv[0]; int fi = s_ri[0];
                #pragma unroll
                for (int k = 1; k < 16; ++k) amax_comb(fb, fi, s_rv[k], s_ri[k]);
                __hip_atomic_store(&pv[((s + 1) * BS + b) * 16 + tile], fb,
                                   __ATOMIC_RELAXED, __HIP_MEMORY_SCOPE_AGENT);
                __hip_atomic_store(&pi[((s + 1) * BS + b) * 16 + tile], fi,
                                   __ATOMIC_RELAXED, __HIP_MEMORY_SCOPE_AGENT);
                __hip_atomic_fetch_add(&cnt[b * 8 + s + 1], 1,
                                       __ATOMIC_RELEASE, __HIP_MEMORY_SCOPE_AGENT);
            }
        }
    }
}

// ---------------------------------------------------------------------------
// Fallback: per-step kernel (kernel-boundary sync) if coop launch fails.
// ---------------------------------------------------------------------------
__global__ __launch_bounds__(1024, 4) void step_kernel(
    const float* __restrict__ rand_pixel, const float* __restrict__ log_sigma_p,
    float* __restrict__ out, float* pv, int* pi, int step)
{
    __shared__ float s_mv[16];
    __shared__ int   s_mi[16];
    __shared__ __align__(16) float s_seed[LAT];
    __shared__ float s_rv[16];
    __shared__ int   s_ri[16];

    const int tid  = threadIdx.x;
    const int b    = blockIdx.x & 63;
    const int tile = blockIdx.x >> 6;
    const int p    = tile * 1024 + tid;

    const float* cfb = out + OFF_CF + (size_t)b * LAT * NPIX;

    const int nmerge = (step == 0) ? 16 : 4;
    if (tid < nmerge) { s_mv[tid] = pv[(step * BS + b) * 16 + tid];
                        s_mi[tid] = pi[(step * BS + b) * 16 + tid]; }
    __syncthreads();
    float bv = -1.0f; int bi = 0;
    for (int k = 0; k < nmerge; ++k) amax_comb(bv, bi, s_mv[k], s_mi[k]);

    if (tid < LAT) s_seed[tid] = cfb[(size_t)tid * NPIX + bi];
    __syncthreads();
    if (tile == 0 && tid < LAT)
        out[OFF_SEEDS + ((size_t)step * BS + b) * LAT + tid] = s_seed[tid];

    float d2 = 0.f;
    #pragma unroll
    for (int c = 0; c < LAT; ++c) {
        float d = cfb[(size_t)c * NPIX + p] - s_seed[c];
        d2 = fmaf(d, d, d2);
    }
    float dist  = sqrtf(fminf(fmaxf(d2, 1e-10f), 1e10f));
    float sigma = expf(log_sigma_p[0]);
    float alpha = expf(-dist / sigma);
    alpha = fminf(fmaxf(alpha, 0.01f), 0.99f);

    float ls  = out[OFF_LOGS + ((size_t)step * BS + b) * NPIX + p];
    float lm  = ls + logf(alpha);
    float lsn = ls + log1pf(-alpha);

    out[OFF_LOGM + ((size_t)step * BS + b) * NPIX + p]       = lm;
    out[OFF_LOGS + ((size_t)(step + 1) * BS + b) * NPIX + p] = lsn;
    if (step == NSTEPS - 1)
        out[OFF_LOGM + ((size_t)NSTEPS * BS + b) * NPIX + p] = lsn;

    if (step < NSTEPS - 1) {
        float prob = rand_pixel[(size_t)b * NPIX + p] * expf(lsn);
        int   idx  = p;
        #pragma unroll
        for (int off = 32; off > 0; off >>= 1) {
            float ov = __shfl_down(prob, off, 64);
            int   oi = __shfl_down(idx, off, 64);
            amax_comb(prob, idx, ov, oi);
        }
        int lane = tid & 63, wid = tid >> 6;
        if (lane == 0) { s_rv[wid] = prob; s_ri[wid] = idx; }
        __syncthreads();
        if (tid == 0) {
            float fb = s_rv[0]; int fi = s_ri[0];
            #pragma unroll
            for (int k = 1; k < 16; ++k) amax_comb(fb, fi, s_rv[k], s_ri[k]);
            pv[((step + 1) * BS + b) * 16 + tile] = fb;
            pi[((step + 1) * BS + b) * 16 + tile] = fi;
        }
    }
}

extern "C" void kernel_launch(void* const* d_in, const int* in_sizes, int n_in,
                              void* d_out, int out_size, void* d_ws, size_t ws_size,
                              hipStream_t stream) {
    const float* x          = (const float*)d_in[0];
    const float* rand_pixel = (const float*)d_in[1];
    const float* w          = (const float*)d_in[2];
    const float* bias       = (const float*)d_in[3];
    const float* gate       = (const float*)d_in[4];
    const float* log_sigma  = (const float*)d_in[5];

    float* out = (float*)d_out;
    // ws: pv[6][64][16] f32 | pi[6][64][16] i32 | cnt[64][8] i32 | gwh 16KB | gwl 16KB
    float* pv  = (float*)d_ws;
    int*   pi  = (int*)((char*)d_ws + 24576);
    int*   cnt = (int*)((char*)d_ws + 49152);
    short* gwh = (short*)((char*)d_ws + 51200);
    short* gwl = (short*)((char*)d_ws + 67584);

    prep_w<<<32, 256, 0, stream>>>(w, gate, gwh, gwl);
    conv_mfma<<<1024, 512, 0, stream>>>(x, rand_pixel, bias, gate, out,
                                        pv, pi, cnt, gwh, gwl);

    const float* a0 = rand_pixel; const float* a1 = log_sigma; float* a2 = out;
    float* a3 = pv; int* a4 = pi; int* a5 = cnt;
    void* kp[6] = {(void*)&a0, (void*)&a1, (void*)&a2, (void*)&a3, (void*)&a4, (void*)&a5};
    hipError_t e = hipLaunchCooperativeKernel((const void*)steps_fused,
                                              dim3(256), dim3(1024), kp, 0, stream);
    if (e != hipSuccess) {
        for (int s = 0; s < NSTEPS; ++s)
            step_kernel<<<256, 1024, 0, stream>>>(rand_pixel, log_sigma, out, pv, pi, s);
    }
}

// Round 20
// 124.342 us; speedup vs baseline: 1.5838x; 1.5838x over previous
//
#include <hip/hip_runtime.h>
#include <hip/hip_bf16.h>

#define NPIX 4096
#define FEAT 128
#define LAT 64
#define BS 64
#define NSTEPS 6

// flat f32 output offsets (log_m_k, log_s_k, c_f, delta, seeds)
#define OFF_LOGM  0u
#define OFF_LOGS  1835008u
#define OFF_CF    3670016u
#define OFF_DELTA 20447232u
#define OFF_SEEDS 20971520u

typedef float f32x4 __attribute__((ext_vector_type(4)));
typedef short s16x8 __attribute__((ext_vector_type(8)));

__device__ __forceinline__ void amax_comb(float& bv, int& bi, float v, int i) {
    if (v > bv || (v == bv && i < bi)) { bv = v; bi = i; }
}

__device__ __forceinline__ short f2bf_rne(float r) {
    __hip_bfloat16 h = __float2bfloat16(r);
    return __builtin_bit_cast(short, h);
}

// split f32 into bf16 hi (truncated -> exact residual) + bf16 lo (RNE of residual)
__device__ __forceinline__ void split2(float v, short& hi, short& lo) {
    unsigned u = __builtin_bit_cast(unsigned, v);
    hi = (short)(u >> 16);
    float hf = __builtin_bit_cast(float, u & 0xFFFF0000u);
    lo = f2bf_rne(v - hf);
}

// 4x4 transpose among the 4 lanes of a quad (b = lane&3).
__device__ __forceinline__ void transpose4(float4& v, int b) {
    float4 w;
    w.x = __shfl_xor(v.x, 1, 64); w.y = __shfl_xor(v.y, 1, 64);
    w.z = __shfl_xor(v.z, 1, 64); w.w = __shfl_xor(v.w, 1, 64);
    float4 u;
    if ((b & 1) == 0) u = make_float4(v.x, w.x, v.z, w.z);
    else              u = make_float4(w.y, v.y, w.w, v.w);
    float4 w2;
    w2.x = __shfl_xor(u.x, 2, 64); w2.y = __shfl_xor(u.y, 2, 64);
    w2.z = __shfl_xor(u.z, 2, 64); w2.w = __shfl_xor(u.w, 2, 64);
    if ((b & 2) == 0) v = make_float4(u.x, u.y, w2.x, w2.y);
    else              v = make_float4(w2.z, w2.w, u.z, u.w);
}

// ---------------------------------------------------------------------------
// K0: split gate*W into bf16 hi/lo in global scratch (16KB each, L2-resident).
// ---------------------------------------------------------------------------
__global__ void prep_w(const float* __restrict__ w, const float* __restrict__ gate_p,
                       short* __restrict__ gwh, short* __restrict__ gwl)
{
    int i = blockIdx.x * 256 + threadIdx.x;   // 8192 total
    float v = gate_p[0] * w[i];
    short h, l; split2(v, h, l);
    gwh[i] = h; gwl[i] = l;
}

// ---------------------------------------------------------------------------
// K1: 1x1 conv via split-bf16 MFMA — ROUND-9 CHAMPION, verbatim.
// 512 thr = 8 waves; wave w: px quarter (w&3)*64, output half (w>>2)*32.
// W and X both read from LDS during compute (lgkmcnt only); per-chunk
// issue-early x loads. grid = 64 b x 16 tiles(256 px) = 1024 blocks.
// ---------------------------------------------------------------------------
__global__ __launch_bounds__(512, 4) void conv_mfma(
    const float* __restrict__ x, const float* __restrict__ rand_pixel,
    const float* __restrict__ bias, const float* __restrict__ gate_p,
    float* __restrict__ out,
    float* __restrict__ pval, int* __restrict__ pidx, int* __restrict__ cnt,
    const short* __restrict__ gwh, const short* __restrict__ gwl)
{
    __shared__ __align__(16) short Xhi[256][40];
    __shared__ __align__(16) short Xlo[256][40];
    __shared__ __align__(16) short Whi[64][132];
    __shared__ __align__(16) short Wlo[64][132];
    __shared__ float sbias[64];

    const int tid  = threadIdx.x;
    const int b    = blockIdx.x >> 4;
    const int tile = blockIdx.x & 15;
    const int p0   = tile * 256;
    const int lane = tid & 63;
    const int wv   = tid >> 6;
    const int l15  = lane & 15;
    const int lg   = lane >> 4;
    const int oh   = wv >> 2;
    const int pxq  = wv & 3;

    const int q  = tid >> 2;
    const int j  = tid & 3;
    const int P  = (q & 63) * 4;
    const int g0 = q >> 6;

    if (tile == 0 && tid < 8) cnt[b * 8 + tid] = 0;
    if (tid < 64) sbias[tid] = gate_p[0] * bias[tid];

    {
        const int o = tid >> 3, c = (tid & 7) * 16;
        *(s16x8*)&Whi[o][c]     = *(const s16x8*)&gwh[o * 128 + c];
        *(s16x8*)&Whi[o][c + 8] = *(const s16x8*)&gwh[o * 128 + c + 8];
        *(s16x8*)&Wlo[o][c]     = *(const s16x8*)&gwl[o * 128 + c];
        *(s16x8*)&Wlo[o][c + 8] = *(const s16x8*)&gwl[o * 128 + c + 8];
    }

    const float* xb = x + (size_t)b * FEAT * NPIX + p0;
    float4 v[4];
    #pragma unroll
    for (int i = 0; i < 4; ++i) {
        int g = g0 + 2 * i;
        v[i] = *(const float4*)(xb + (size_t)(g * 4 + j) * NPIX + P);
    }
    #pragma unroll
    for (int i = 0; i < 4; ++i) {
        int g = g0 + 2 * i;
        float4 t = v[i]; transpose4(t, j);
        short h0, l0, h1, l1, h2, l2, h3, l3;
        split2(t.x, h0, l0); split2(t.y, h1, l1);
        split2(t.z, h2, l2); split2(t.w, h3, l3);
        *(short4*)&Xhi[P + j][g * 4] = make_short4(h0, h1, h2, h3);
        *(short4*)&Xlo[P + j][g * 4] = make_short4(l0, l1, l2, l3);
    }
    __syncthreads();

    f32x4 acc[2][4];
    #pragma unroll
    for (int og2 = 0; og2 < 2; ++og2)
        #pragma unroll
        for (int pg = 0; pg < 4; ++pg)
            acc[og2][pg] = (f32x4){0.f, 0.f, 0.f, 0.f};

    #pragma unroll
    for (int kc = 0; kc < 4; ++kc) {
        if (kc < 3) {
            #pragma unroll
            for (int i = 0; i < 4; ++i) {
                int g = g0 + 2 * i;
                v[i] = *(const float4*)(xb + (size_t)((kc + 1) * 32 + g * 4 + j) * NPIX + P);
            }
        }

        s16x8 Ah[2], Al[2];
        #pragma unroll
        for (int og2 = 0; og2 < 2; ++og2) {
            int o = oh * 32 + og2 * 16 + l15;
            Ah[og2] = *(const s16x8*)&Whi[o][kc * 32 + lg * 8];
            Al[og2] = *(const s16x8*)&Wlo[o][kc * 32 + lg * 8];
        }

        #pragma unroll
        for (int pg = 0; pg < 4; ++pg) {
            int pxl = pxq * 64 + pg * 16 + l15;
            s16x8 Bh = *(const s16x8*)&Xhi[pxl][lg * 8];
            s16x8 Bl = *(const s16x8*)&Xlo[pxl][lg * 8];
            #pragma unroll
            for (int og2 = 0; og2 < 2; ++og2) {
                acc[og2][pg] = __builtin_amdgcn_mfma_f32_16x16x32_bf16(Ah[og2], Bh, acc[og2][pg], 0, 0, 0);
                acc[og2][pg] = __builtin_amdgcn_mfma_f32_16x16x32_bf16(Ah[og2], Bl, acc[og2][pg], 0, 0, 0);
                acc[og2][pg] = __builtin_amdgcn_mfma_f32_16x16x32_bf16(Al[og2], Bh, acc[og2][pg], 0, 0, 0);
            }
        }

        if (kc < 3) {
            __syncthreads();
            #pragma unroll
            for (int i = 0; i < 4; ++i) {
                int g = g0 + 2 * i;
                float4 t = v[i]; transpose4(t, j);
                short h0, l0, h1, l1, h2, l2, h3, l3;
                split2(t.x, h0, l0); split2(t.y, h1, l1);
                split2(t.z, h2, l2); split2(t.w, h3, l3);
                *(short4*)&Xhi[P + j][g * 4] = make_short4(h0, h1, h2, h3);
                *(short4*)&Xlo[P + j][g * 4] = make_short4(l0, l1, l2, l3);
            }
            __syncthreads();
        }
    }

    float* cf = out + OFF_CF + (size_t)b * LAT * NPIX;
    #pragma unroll
    for (int og2 = 0; og2 < 2; ++og2) {
        #pragma unroll
        for (int pg = 0; pg < 4; ++pg) {
            #pragma unroll
            for (int r = 0; r < 4; ++r) {
                int o = oh * 32 + og2 * 16 + lg * 4 + r;
                int p = p0 + pxq * 64 + pg * 16 + l15;
                float vv = acc[og2][pg][r] + sbias[o];
                if (o == 62) {
                    out[OFF_DELTA + ((size_t)b * 2 + 0) * NPIX + p] = vv;
                    vv += (float)(-1.0 + 2.0 * (double)(p >> 6) / 63.0);
                } else if (o == 63) {
                    out[OFF_DELTA + ((size_t)b * 2 + 1) * NPIX + p] = vv;
                    vv += (float)(-1.0 + 2.0 * (double)(p & 63) / 63.0);
                }
                cf[(size_t)o * NPIX + p] = vv;
            }
        }
    }

    if (wv == 0) {
        *(float4*)(out + OFF_LOGS + (size_t)b * NPIX + p0 + lane * 4) =
            make_float4(0.f, 0.f, 0.f, 0.f);
        float4 rv = *(const float4*)(rand_pixel + (size_t)b * NPIX + p0 + lane * 4);
        int pb = p0 + lane * 4;
        float bv = rv.x; int bi = pb;
        if (rv.y > bv) { bv = rv.y; bi = pb + 1; }
        if (rv.z > bv) { bv = rv.z; bi = pb + 2; }
        if (rv.w > bv) { bv = rv.w; bi = pb + 3; }
        #pragma unroll
        for (int off = 32; off > 0; off >>= 1) {
            float ov = __shfl_down(bv, off, 64);
            int   oi = __shfl_down(bi, off, 64);
            amax_comb(bv, bi, ov, oi);
        }
        if (lane == 0) { pval[blockIdx.x] = bv; pidx[blockIdx.x] = bi; }
    }
}

// 16 groups of 4 channels
#define REP16(OP) OP(0) OP(1) OP(2) OP(3) OP(4) OP(5) OP(6) OP(7) \
                  OP(8) OP(9) OP(10) OP(11) OP(12) OP(13) OP(14) OP(15)

// ---------------------------------------------------------------------------
// K2: fused 6-step clustering — r16 champion:
// (1) cr[64] EXPLICITLY PARKED IN AGPRs via v_accvgpr_write/read ("a" asm
//     constraints): the unified gfx950 file gives 64 arch + 64 acc = 128/wave
//     at 4 waves/SIMD, so the 64-arch-VGPR allocator cap no longer forces a
//     scratch spill (the invariant cost of every prior steps variant).
// (2) XCD-LOCAL batch decode: b = blk&63, tile = blk>>6 -> a batch's 4 blocks
//     are {b, b+64, b+128, b+192} === b (mod 8) -> same XCD under round-robin
//     dispatch: cnt/pv polling and the 1MB c_f slice become XCD-L2-local.
// Block = 1024 thr = 1024 px, grid 256, quorum-4 spin sync; pv/pi slots.
// ---------------------------------------------------------------------------
__global__ __launch_bounds__(1024, 4) void steps_fused(
    const float* __restrict__ rand_pixel, const float* __restrict__ log_sigma_p,
    float* __restrict__ out, float* pv, int* pi, int* cnt)
{
    __shared__ float s_mv[16];
    __shared__ int   s_mi[16];
    __shared__ __align__(16) float s_seed[LAT];
    __shared__ float s_rv[16];
    __shared__ int   s_ri[16];

    const int tid  = threadIdx.x;
    const int b    = blockIdx.x & 63;    // XCD-local decode
    const int tile = blockIdx.x >> 6;    // 0..3
    const int p    = tile * 1024 + tid;

    const float* cfb = out + OFF_CF + (size_t)b * LAT * NPIX;

    // cr[64] parked in AGPRs: declare 64 AGPR-resident floats, write once.
#define AG_DECL(i) float ag##i##_0, ag##i##_1, ag##i##_2, ag##i##_3;
    REP16(AG_DECL)
#define AG_PARK(i) { \
    float v0 = cfb[(size_t)(4*i+0)*NPIX + p]; \
    float v1 = cfb[(size_t)(4*i+1)*NPIX + p]; \
    float v2 = cfb[(size_t)(4*i+2)*NPIX + p]; \
    float v3 = cfb[(size_t)(4*i+3)*NPIX + p]; \
    asm volatile("v_accvgpr_write_b32 %0, %1" : "=a"(ag##i##_0) : "v"(v0)); \
    asm volatile("v_accvgpr_write_b32 %0, %1" : "=a"(ag##i##_1) : "v"(v1)); \
    asm volatile("v_accvgpr_write_b32 %0, %1" : "=a"(ag##i##_2) : "v"(v2)); \
    asm volatile("v_accvgpr_write_b32 %0, %1" : "=a"(ag##i##_3) : "v"(v3)); }
    REP16(AG_PARK)

    const float rp    = rand_pixel[(size_t)b * NPIX + p];
    const float sigma = expf(log_sigma_p[0]);
    float ls = 0.f;

    #pragma unroll 1
    for (int s = 0; s < NSTEPS; ++s) {
        if (s > 0) {
            if (tid == 0) {
                while (__hip_atomic_load(&cnt[b * 8 + s], __ATOMIC_ACQUIRE,
                                         __HIP_MEMORY_SCOPE_AGENT) < 4)
                    __builtin_amdgcn_s_sleep(2);
            }
            __syncthreads();
        }
        const int nmerge = (s == 0) ? 16 : 4;
        if (tid < nmerge) {
            s_mv[tid] = __hip_atomic_load(&pv[(s * BS + b) * 16 + tid],
                                          __ATOMIC_RELAXED, __HIP_MEMORY_SCOPE_AGENT);
            s_mi[tid] = __hip_atomic_load(&pi[(s * BS + b) * 16 + tid],
                                          __ATOMIC_RELAXED, __HIP_MEMORY_SCOPE_AGENT);
        }
        __syncthreads();

        float bv = -1.0f; int bi = 0;
        for (int k = 0; k < nmerge; ++k) amax_comb(bv, bi, s_mv[k], s_mi[k]);

        if (tid < LAT) s_seed[tid] = cfb[(size_t)tid * NPIX + bi];
        __syncthreads();
        if (tile == 0 && tid < LAT)
            out[OFF_SEEDS + ((size_t)s * BS + b) * LAT + tid] = s_seed[tid];

        // d2 = sum (c - s)^2, channels unparked from AGPRs (1 VALU op each)
        float d2 = 0.f;
#define AG_DIFF(i) { \
        float c0, c1, c2, c3; \
        asm volatile("v_accvgpr_read_b32 %0, %1" : "=v"(c0) : "a"(ag##i##_0)); \
        asm volatile("v_accvgpr_read_b32 %0, %1" : "=v"(c1) : "a"(ag##i##_1)); \
        asm volatile("v_accvgpr_read_b32 %0, %1" : "=v"(c2) : "a"(ag##i##_2)); \
        asm volatile("v_accvgpr_read_b32 %0, %1" : "=v"(c3) : "a"(ag##i##_3)); \
        float e0 = c0 - s_seed[4*i+0]; d2 = fmaf(e0, e0, d2); \
        float e1 = c1 - s_seed[4*i+1]; d2 = fmaf(e1, e1, d2); \
        float e2 = c2 - s_seed[4*i+2]; d2 = fmaf(e2, e2, d2); \
        float e3 = c3 - s_seed[4*i+3]; d2 = fmaf(e3, e3, d2); }
        REP16(AG_DIFF)

        float dist  = sqrtf(fminf(fmaxf(d2, 1e-10f), 1e10f));
        float alpha = expf(-dist / sigma);
        alpha = fminf(fmaxf(alpha, 0.01f), 0.99f);
        float lm  = ls + logf(alpha);
        float lsn = ls + log1pf(-alpha);

        out[OFF_LOGM + ((size_t)s * BS + b) * NPIX + p]       = lm;
        out[OFF_LOGS + ((size_t)(s + 1) * BS + b) * NPIX + p] = lsn;
        ls = lsn;

        if (s == NSTEPS - 1) {
            out[OFF_LOGM + ((size_t)NSTEPS * BS + b) * NPIX + p] = lsn;
        } else {
            float prob = rp * expf(lsn);
            int   idx  = p;
            #pragma unroll
            for (int off = 32; off > 0; off >>= 1) {
                float ov = __shfl_down(prob, off, 64);
                int   oi = __shfl_down(idx, off, 64);
                amax_comb(prob, idx, ov, oi);
            }
            int lane = tid & 63, wid = tid >> 6;
            if (lane == 0) { s_rv[wid] = prob; s_ri[wid] = idx; }
            __syncthreads();
            if (tid == 0) {
                float fb = s_rv[0]; int fi = s_ri[0];
                #pragma unroll
                for (int k = 1; k < 16; ++k) amax_comb(fb, fi, s_rv[k], s_ri[k]);
                __hip_atomic_store(&pv[((s + 1) * BS + b) * 16 + tile], fb,
                                   __ATOMIC_RELAXED, __HIP_MEMORY_SCOPE_AGENT);
                __hip_atomic_store(&pi[((s + 1) * BS + b) * 16 + tile], fi,
                                   __ATOMIC_RELAXED, __HIP_MEMORY_SCOPE_AGENT);
                __hip_atomic_fetch_add(&cnt[b * 8 + s + 1], 1,
                                       __ATOMIC_RELEASE, __HIP_MEMORY_SCOPE_AGENT);
            }
        }
    }
}

// ---------------------------------------------------------------------------
// Fallback: per-step kernel (kernel-boundary sync) if coop launch fails.
// ---------------------------------------------------------------------------
__global__ __launch_bounds__(1024, 4) void step_kernel(
    const float* __restrict__ rand_pixel, const float* __restrict__ log_sigma_p,
    float* __restrict__ out, float* pv, int* pi, int step)
{
    __shared__ float s_mv[16];
    __shared__ int   s_mi[16];
    __shared__ __align__(16) float s_seed[LAT];
    __shared__ float s_rv[16];
    __shared__ int   s_ri[16];

    const int tid  = threadIdx.x;
    const int b    = blockIdx.x & 63;
    const int tile = blockIdx.x >> 6;
    const int p    = tile * 1024 + tid;

    const float* cfb = out + OFF_CF + (size_t)b * LAT * NPIX;

    const int nmerge = (step == 0) ? 16 : 4;
    if (tid < nmerge) { s_mv[tid] = pv[(step * BS + b) * 16 + tid];
                        s_mi[tid] = pi[(step * BS + b) * 16 + tid]; }
    __syncthreads();
    float bv = -1.0f; int bi = 0;
    for (int k = 0; k < nmerge; ++k) amax_comb(bv, bi, s_mv[k], s_mi[k]);

    if (tid < LAT) s_seed[tid] = cfb[(size_t)tid * NPIX + bi];
    __syncthreads();
    if (tile == 0 && tid < LAT)
        out[OFF_SEEDS + ((size_t)step * BS + b) * LAT + tid] = s_seed[tid];

    float d2 = 0.f;
    #pragma unroll
    for (int c = 0; c < LAT; ++c) {
        float d = cfb[(size_t)c * NPIX + p] - s_seed[c];
        d2 = fmaf(d, d, d2);
    }
    float dist  = sqrtf(fminf(fmaxf(d2, 1e-10f), 1e10f));
    float sigma = expf(log_sigma_p[0]);
    float alpha = expf(-dist / sigma);
    alpha = fminf(fmaxf(alpha, 0.01f), 0.99f);

    float ls  = out[OFF_LOGS + ((size_t)step * BS + b) * NPIX + p];
    float lm  = ls + logf(alpha);
    float lsn = ls + log1pf(-alpha);

    out[OFF_LOGM + ((size_t)step * BS + b) * NPIX + p]       = lm;
    out[OFF_LOGS + ((size_t)(step + 1) * BS + b) * NPIX + p] = lsn;
    if (step == NSTEPS - 1)
        out[OFF_LOGM + ((size_t)NSTEPS * BS + b) * NPIX + p] = lsn;

    if (step < NSTEPS - 1) {
        float prob = rand_pixel[(size_t)b * NPIX + p] * expf(lsn);
        int   idx  = p;
        #pragma unroll
        for (int off = 32; off > 0; off >>= 1) {
            float ov = __shfl_down(prob, off, 64);
            int   oi = __shfl_down(idx, off, 64);
            amax_comb(prob, idx, ov, oi);
        }
        int lane = tid & 63, wid = tid >> 6;
        if (lane == 0) { s_rv[wid] = prob; s_ri[wid] = idx; }
        __syncthreads();
        if (tid == 0) {
            float fb = s_rv[0]; int fi = s_ri[0];
            #pragma unroll
            for (int k = 1; k < 16; ++k) amax_comb(fb, fi, s_rv[k], s_ri[k]);
            pv[((step + 1) * BS + b) * 16 + tile] = fb;
            pi[((step + 1) * BS + b) * 16 + tile] = fi;
        }
    }
}

extern "C" void kernel_launch(void* const* d_in, const int* in_sizes, int n_in,
                              void* d_out, int out_size, void* d_ws, size_t ws_size,
                              hipStream_t stream) {
    const float* x          = (const float*)d_in[0];
    const float* rand_pixel = (const float*)d_in[1];
    const float* w          = (const float*)d_in[2];
    const float* bias       = (const float*)d_in[3];
    const float* gate       = (const float*)d_in[4];
    const float* log_sigma  = (const float*)d_in[5];

    float* out = (float*)d_out;
    // ws: pv[6][64][16] f32 | pi[6][64][16] i32 | cnt[64][8] i32 | gwh 16KB | gwl 16KB
    float* pv  = (float*)d_ws;
    int*   pi  = (int*)((char*)d_ws + 24576);
    int*   cnt = (int*)((char*)d_ws + 49152);
    short* gwh = (short*)((char*)d_ws + 51200);
    short* gwl = (short*)((char*)d_ws + 67584);

    prep_w<<<32, 256, 0, stream>>>(w, gate, gwh, gwl);
    conv_mfma<<<1024, 512, 0, stream>>>(x, rand_pixel, bias, gate, out,
                                        pv, pi, cnt, gwh, gwl);

    const float* a0 = rand_pixel; const float* a1 = log_sigma; float* a2 = out;
    float* a3 = pv; int* a4 = pi; int* a5 = cnt;
    void* kp[6] = {(void*)&a0, (void*)&a1, (void*)&a2, (void*)&a3, (void*)&a4, (void*)&a5};
    hipError_t e = hipLaunchCooperativeKernel((const void*)steps_fused,
                                              dim3(256), dim3(1024), kp, 0, stream);
    if (e != hipSuccess) {
        for (int s = 0; s < NSTEPS; ++s)
            step_kernel<<<256, 1024, 0, stream>>>(rand_pixel, log_sigma, out, pv, pi, s);
    }
}